// Round 8
// baseline (70.423 us; speedup 1.0000x reference)
//
#include <hip/hip_runtime.h>
#include <hip/hip_bf16.h>

#define B_ROWS 32768
#define D_IN   128
#define H1_    256
#define HTAU   32
#define NBLK   128

#define NE     64
#define SMIN  (-8.0f)
#define SMAX  ( 8.0f)

typedef __bf16 bf16_t;
typedef bf16_t bf16x8 __attribute__((ext_vector_type(8)));
typedef float  f32x4  __attribute__((ext_vector_type(4)));

__device__ __forceinline__ bf16x8 cvt8(const float* v) {
    bf16x8 r;
#pragma unroll
    for (int i = 0; i < 8; ++i) r[i] = (bf16_t)v[i];
    return r;
}

// async global->LDS, 16B/lane; LDS dest = wave-uniform base + lane*16
__device__ __forceinline__ void gload_lds16(const void* g, void* l) {
    __builtin_amdgcn_global_load_lds(
        (const __attribute__((address_space(1))) uint32_t*)g,
        (__attribute__((address_space(3))) uint32_t*)l, 16, 0, 0);
}

// ---------------------------------------------------------------------------
// prep: blocks [0,128):  tau table pairs tab2[n][e] = (f_n(s_e), f_n(s_{e+1}))
//   n = bid; 4 waves split the h-sum (8 each), LDS reduce, wave 0 stores.
//       blocks [128,176): W1,W2 -> bf16 in MFMA fragment order
// ---------------------------------------------------------------------------
__global__ void prep(const float* __restrict__ w1, const float* __restrict__ w2,
                     const float* __restrict__ wt1, const float* __restrict__ bt1,
                     const float* __restrict__ wt2, const float* __restrict__ bt2,
                     float2* __restrict__ tab2,
                     bf16x8* __restrict__ w1f, bf16x8* __restrict__ w2f) {
    __shared__ float ps[4][64];
    const int bid = blockIdx.x, tid = threadIdx.x;
    if (bid < NBLK) {
        const int n  = bid;
        const int e  = tid & 63;
        const int hh = tid >> 6;
        float s = SMIN + (SMAX - SMIN) * (float)e / (float)(NE - 1);
        float part = (hh == 0) ? bt2[n] : 0.f;
#pragma unroll
        for (int j = 0; j < 8; ++j) {
            int h = hh * 8 + j;
            float z  = s * wt1[n * HTAU + h] + bt1[n * HTAU + h];
            float sp = (z > 20.f) ? z : log1pf(expf(z));
            part += wt2[n * HTAU + h] * sp;
        }
        ps[hh][e] = part;
        __syncthreads();
        if (hh == 0) {
            float acc = ps[0][e] + ps[1][e] + ps[2][e] + ps[3][e];
            float nxt = __shfl_down(acc, 1, 64);
            tab2[n * NE + e] = make_float2(acc, nxt);
        }
    } else {
        const int cid  = (bid - NBLK) * 256 + tid;
        const int isW2 = cid >= 4096;
        const int c2   = isW2 ? cid - 4096 : cid;
        const int kk = c2 >> 10, c = c2 & 1023;
        const int nf = c >> 6,  ll = c & 63;
        const int col = nf * 16 + (ll & 15);
        const int kr  = kk * 32 + (ll >> 4) * 8;
        const float* src = isW2 ? (w2 + col * H1_ + kr) : (w1 + col * D_IN + kr);
        float tmp[8];
        *(f32x4*)tmp       = *(const f32x4*)src;
        *(f32x4*)(tmp + 4) = *(const f32x4*)(src + 4);
        (isW2 ? w2f : w1f)[c2] = cvt8(tmp);
    }
}

// ---------------------------------------------------------------------------
// fused_main: identical to r7 (best: 33.2us). This round launches it 3x as a
// timing probe: idempotent (pure function of inputs), so output unchanged;
// delta vs r7 = 2 x T(fused_main).
// ---------------------------------------------------------------------------
__global__ __launch_bounds__(256, 2)
void fused_main(const float* __restrict__ x,
                const bf16x8* __restrict__ w1f, const bf16x8* __restrict__ w2f,
                const float* __restrict__ b1, const float* __restrict__ b2,
                const float* __restrict__ w3, const float* __restrict__ b3,
                const float2* __restrict__ tab2, const float* __restrict__ wlr,
                const float* __restrict__ blr,
                float* __restrict__ mu_out, float* __restrict__ lr_out) {
    __shared__ bf16x8 wsl[2048];         // 32KB: one 64-K W slice (frag order)
    __shared__ char   h1_raw[64 * 512];  // 32KB bf16 [64][256], swizzled

    const int tid = threadIdx.x;
    const int l   = tid & 63;
    const int w   = tid >> 6;
    const int q   = l >> 4;
    const int l15 = l & 15;
    const int row = w * 16 + l15;
    const int rb  = blockIdx.x * 64;

    // ---- prologue: x loads FIRST (HBM, longest pole) ----
    float xv[32], wlv[32];
    {
        const float* xr = x + (size_t)(rb + row) * D_IN;
#pragma unroll
        for (int kk = 0; kk < 4; ++kk) {
            *(f32x4*)(xv + kk * 8)     = *(const f32x4*)(xr + kk * 32 + q * 8);
            *(f32x4*)(xv + kk * 8 + 4) = *(const f32x4*)(xr + kk * 32 + q * 8 + 4);
        }
    }
#pragma unroll
    for (int j = 0; j < 8; ++j)
        gload_lds16(w1f + w * 512 + j * 64 + l, &wsl[w * 512 + j * 64]);
#pragma unroll
    for (int kk = 0; kk < 4; ++kk) {
        *(f32x4*)(wlv + kk * 8)     = *(const f32x4*)(wlr + kk * 32 + q * 8);
        *(f32x4*)(wlv + kk * 8 + 4) = *(const f32x4*)(wlr + kk * 32 + q * 8 + 4);
    }
    bf16x8 a1[4];
#pragma unroll
    for (int kk = 0; kk < 4; ++kk) a1[kk] = cvt8(xv + kk * 8);

    // ---- tau branch (store deferred to tail) ----
    float tsum = 0.f;
    {
        const float INVDS = (float)(NE - 1) / (SMAX - SMIN);
#pragma unroll
        for (int kk = 0; kk < 4; ++kk) {
#pragma unroll
            for (int i = 0; i < 8; ++i) {
                float s = xv[kk * 8 + i];
                s = fminf(fmaxf(s, SMIN), SMAX);
                float u = (s - SMIN) * INVDS;
                int ii = (int)u;
                ii = ii > NE - 2 ? NE - 2 : ii;
                float fr = u - (float)ii;
                int n = kk * 32 + q * 8 + i;
                float2 tv = tab2[n * NE + ii];
                tsum += wlv[kk * 8 + i] * (tv.x + (tv.y - tv.x) * fr);
            }
        }
        tsum += __shfl_xor(tsum, 16, 64);
        tsum += __shfl_xor(tsum, 32, 64);
    }

    f32x4 acc[16];
#pragma unroll
    for (int f = 0; f < 16; ++f) acc[f] = (f32x4){0.f, 0.f, 0.f, 0.f};

    // ---- mu layer 1 (K = 128, 2 K-steps of 64) ----
#pragma unroll
    for (int s = 0; s < 2; ++s) {
        __syncthreads();
#pragma unroll
        for (int kh = 0; kh < 2; ++kh)
#pragma unroll
            for (int nf = 0; nf < 16; ++nf)
                acc[nf] = __builtin_amdgcn_mfma_f32_16x16x32_bf16(
                    a1[s * 2 + kh], wsl[kh * 1024 + nf * 64 + l], acc[nf], 0, 0, 0);

        if (s == 1) {
#pragma unroll
            for (int f = 0; f < 16; ++f) {
                int col = f * 16 + l15;
                float bias = b1[col];
#pragma unroll
                for (int r = 0; r < 4; ++r) {
                    int gr = w * 16 + q * 4 + r;
                    float v = acc[f][r] + bias;
                    v = v > 0.f ? v : 0.f;
                    int byte = (gr * 512 + col * 2) ^ ((gr & 7) << 4);
                    *(bf16_t*)(h1_raw + byte) = (bf16_t)v;
                }
                acc[f] = (f32x4){0.f, 0.f, 0.f, 0.f};
            }
        }
        __syncthreads();
        const bf16x8* nsrc = (s == 0) ? (w1f + 2048) : w2f;
#pragma unroll
        for (int j = 0; j < 8; ++j)
            gload_lds16(nsrc + w * 512 + j * 64 + l, &wsl[w * 512 + j * 64]);
    }

    // ---- mu layer 2 (K = 256, 4 K-steps of 64) ----
#pragma unroll
    for (int s = 0; s < 4; ++s) {
        __syncthreads();
#pragma unroll
        for (int kh = 0; kh < 2; ++kh) {
            int k0   = (s * 2 + kh) * 32 + q * 8;
            int byte = (row * 512 + k0 * 2) ^ ((row & 7) << 4);
            bf16x8 a = *(bf16x8*)(h1_raw + byte);
#pragma unroll
            for (int nf = 0; nf < 16; ++nf)
                acc[nf] = __builtin_amdgcn_mfma_f32_16x16x32_bf16(
                    a, wsl[kh * 1024 + nf * 64 + l], acc[nf], 0, 0, 0);
        }
        if (s < 3) {
            __syncthreads();
#pragma unroll
            for (int j = 0; j < 8; ++j)
                gload_lds16(w2f + (s + 1) * 2048 + w * 512 + j * 64 + l,
                            &wsl[w * 512 + j * 64]);
        }
    }

    // ---- epilogue 2: mu = relu(acc + b2) . w3 + b3 ----
    float p[4] = {0.f, 0.f, 0.f, 0.f};
#pragma unroll
    for (int f = 0; f < 16; ++f) {
        int col = f * 16 + l15;
        float bias = b2[col];
        float wv   = w3[col];
#pragma unroll
        for (int r = 0; r < 4; ++r) {
            float v = acc[f][r] + bias;
            v = v > 0.f ? v : 0.f;
            p[r] += v * wv;
        }
    }
#pragma unroll
    for (int m = 1; m < 16; m <<= 1) {
#pragma unroll
        for (int r = 0; r < 4; ++r) p[r] += __shfl_xor(p[r], m, 64);
    }
    if (l15 == 0) {
        float bb = b3[0];
#pragma unroll
        for (int r = 0; r < 4; ++r)
            mu_out[rb + w * 16 + q * 4 + r] = p[r] + bb;
    }
    if (q == 0) lr_out[rb + row] = tsum + blr[0];
}

extern "C" void kernel_launch(void* const* d_in, const int* in_sizes, int n_in,
                              void* d_out, int out_size, void* d_ws, size_t ws_size,
                              hipStream_t stream) {
    const float* x   = (const float*)d_in[0];
    const float* w1  = (const float*)d_in[1];
    const float* b1  = (const float*)d_in[2];
    const float* w2  = (const float*)d_in[3];
    const float* b2  = (const float*)d_in[4];
    const float* w3  = (const float*)d_in[5];
    const float* b3  = (const float*)d_in[6];
    const float* wt1 = (const float*)d_in[7];
    const float* bt1 = (const float*)d_in[8];
    const float* wt2 = (const float*)d_in[9];
    const float* bt2 = (const float*)d_in[10];
    const float* wlr = (const float*)d_in[11];
    const float* blr = (const float*)d_in[12];

    float* out    = (float*)d_out;
    float* mu_out = out;                 // output 0: mu     [32768]
    float* lr_out = out + B_ROWS;        // output 1: out_lr [32768]

    char* ws = (char*)d_ws;
    float2* tab2 = (float2*)ws;                   // 64KB
    bf16x8* w1f  = (bf16x8*)(ws + (64 << 10));    // 64KB
    bf16x8* w2f  = (bf16x8*)(ws + (128 << 10));   // 128KB

    prep<<<NBLK + 48, 256, 0, stream>>>(w1, w2, wt1, bt1, wt2, bt2, tab2, w1f, w2f);
    // TIMING PROBE: fused_main is idempotent; launch 3x.
    // delta vs r7's single launch = 2 x T(fused_main).
    fused_main<<<B_ROWS / 64, 256, 0, stream>>>(x, w1f, w2f, b1, b2, w3, b3,
                                                tab2, wlr, blr, mu_out, lr_out);
    fused_main<<<B_ROWS / 64, 256, 0, stream>>>(x, w1f, w2f, b1, b2, w3, b3,
                                                tab2, wlr, blr, mu_out, lr_out);
    fused_main<<<B_ROWS / 64, 256, 0, stream>>>(x, w1f, w2f, b1, b2, w3, b3,
                                                tab2, wlr, blr, mu_out, lr_out);
}